// Round 3
// baseline (613.890 us; speedup 1.0000x reference)
//
#include <hip/hip_runtime.h>
#include <math.h>

// Problem constants
#define NPIX   131072      // 32*64*64 pixels
#define KCODES 512
#define DIM    64
#define HW     4096        // 64*64
#define CHW    262144      // 64*4096

// Output layout (floats, concatenated in reference return order)
// [0]            quant_loss (1)
// [1]            quantized  (8388608)   [B,C,H,W]
// [8388609]      perplexity (1)
// [8388610]      encodings  (67108864)  [N,512]
// [75497474]     idx        (131072)
#define O_Q    1ll
#define O_PERP 8388609ll
#define O_ENC  8388610ll
#define O_IDX  75497474ll

// ws layout (floats): [0] loss accum, [1..512] counts (u32), [513..1024] esq

// Replicate numpy pairwise_sum of x**2 for n=64:
// 8 accumulators over stride-8 slices, combined ((r0+r1)+(r2+r3))+((r4+r5)+(r6+r7)).
__device__ __forceinline__ float np_sumsq64(const float (&x)[64]) {
#pragma clang fp contract(off)
  float r0 = x[0]*x[0], r1 = x[1]*x[1], r2 = x[2]*x[2], r3 = x[3]*x[3];
  float r4 = x[4]*x[4], r5 = x[5]*x[5], r6 = x[6]*x[6], r7 = x[7]*x[7];
#pragma unroll
  for (int i = 8; i < 64; i += 8) {
    r0 += x[i+0]*x[i+0];
    r1 += x[i+1]*x[i+1];
    r2 += x[i+2]*x[i+2];
    r3 += x[i+3]*x[i+3];
    r4 += x[i+4]*x[i+4];
    r5 += x[i+5]*x[i+5];
    r6 += x[i+6]*x[i+6];
    r7 += x[i+7]*x[i+7];
  }
  return ((r0+r1)+(r2+r3))+((r4+r5)+(r6+r7));
}

// Prep: zero loss accumulator + counts, compute esq[k] (np-pairwise) into ws.
__global__ void vq_prep(const float* __restrict__ emb, float* __restrict__ ws) {
  const int t = threadIdx.x;  // 512 threads
  if (t == 0) ws[0] = 0.0f;
  ((unsigned*)ws)[1 + t] = 0u;
  float x[64];
  const float* e = emb + t * DIM;
#pragma unroll
  for (int d = 0; d < 64; ++d) x[d] = e[d];
  ws[513 + t] = np_sumsq64(x);
}

// Main: one thread = one pixel. __launch_bounds__(256,2): grid gives exactly
// 2 waves/SIMD, so declare that -> VGPR cap 256 -> za[64] stays resident
// (round 2 had VGPR_Count=48: za was spilled, inner loop reloaded it).
// Embedding rows are wave-uniform; two-buffer software pipeline loads row k+1
// while computing dot(row k) to hide K$/L2 latency. The dot is a single
// ascending-d fp32 FMA chain (mirrors OpenBLAS sgemm accumulation); strict <
// keeps lowest index on fp32 ties, matching np.argmin.
__global__ __launch_bounds__(256, 2) void vq_main(
    const float* __restrict__ z, const float* __restrict__ emb,
    float* __restrict__ out, float* __restrict__ ws)
{
  __shared__ unsigned hist[KCODES];     // per-block histogram
  __shared__ unsigned short ridx[256];  // per-row argmin for encodings write
  __shared__ float wsum[4];

  const int t   = threadIdx.x;
  const int blk = blockIdx.x;
  const int n   = blk * 256 + t;        // pixel id, grid = 512 blocks

  hist[t] = 0u;
  hist[t + 256] = 0u;

  // Load this pixel's z vector into registers ([B,C,H,W]: stride HW over c)
  float za[DIM];
  {
    const float* p0 = z + (size_t)(n >> 12) * CHW + (n & 4095);
#pragma unroll
    for (int d = 0; d < DIM; ++d) za[d] = p0[(size_t)d * HW];
  }
  const float zsqa = np_sumsq64(za);

  const float* __restrict__ esq = ws + 513;
  float best = INFINITY;
  int bi = 0;

  // Two-buffer software pipeline over codes.
  float ea[DIM], eb[DIM];
#pragma unroll
  for (int d = 0; d < DIM; ++d) ea[d] = emb[d];   // row 0

  for (int k = 0; k < KCODES; k += 2) {
    // issue loads for row k+1 while dotting row k
    const float* __restrict__ e1 = emb + ((k + 1) << 6);
#pragma unroll
    for (int d = 0; d < DIM; ++d) eb[d] = e1[d];

    float dot0 = 0.0f;
#pragma unroll
    for (int d = 0; d < DIM; ++d) dot0 = fmaf(za[d], ea[d], dot0);
    {
      const float dist = (zsqa + esq[k]) - 2.0f * dot0;  // same rounding as np
      if (dist < best) { best = dist; bi = k; }
    }

    // issue loads for row k+2 (wraps harmlessly at the end) while dotting k+1
    const float* __restrict__ e2 = emb + (((k + 2) & 511) << 6);
#pragma unroll
    for (int d = 0; d < DIM; ++d) ea[d] = e2[d];

    float dot1 = 0.0f;
#pragma unroll
    for (int d = 0; d < DIM; ++d) dot1 = fmaf(za[d], eb[d], dot1);
    {
      const float dist = (zsqa + esq[k + 1]) - 2.0f * dot1;
      if (dist < best) { best = dist; bi = k + 1; }
    }
  }

  // ---- epilogue ----
  atomicAdd(&hist[bi], 1u);
  ridx[t] = (unsigned short)bi;
  out[O_IDX + n] = (float)bi;

  // quantized output (transposed back to [B,C,H,W]) + loss partial
  float lsum = 0.0f;
  {
    const float* e0 = emb + ((size_t)bi << 6);
    float* q0 = out + O_Q + (size_t)(n >> 12) * CHW + (n & 4095);
#pragma unroll
    for (int d = 0; d < DIM; ++d) {
      const float ev = e0[d];
      const float df = ev - za[d];
      lsum = fmaf(df, df, lsum);
      q0[(size_t)d * HW] = ev;
    }
  }
  // wave + block reduce of loss
#pragma unroll
  for (int off = 32; off > 0; off >>= 1) lsum += __shfl_down(lsum, off, 64);
  if ((t & 63) == 0) wsum[t >> 6] = lsum;
  __syncthreads();  // also publishes hist[] and ridx[]
  if (t == 0) atomicAdd(ws, (wsum[0] + wsum[1]) + (wsum[2] + wsum[3]));

  unsigned* counts = (unsigned*)ws + 1;
  atomicAdd(&counts[t],       hist[t]);
  atomicAdd(&counts[t + 256], hist[t + 256]);

  // encodings: 256 rows x 512 floats per block, one-hot. float2 stores
  // (O_ENC is only 8-byte aligned). Coalesced: consecutive threads write
  // consecutive float2.
  float2* enc = (float2*)(out + O_ENC) + (size_t)blk * (256 * 256);
  for (int i = t; i < 256 * 256; i += 256) {
    const int r  = i >> 8;        // row (local pixel)
    const int c2 = i & 255;       // float2 index within row
    const unsigned bv = ridx[r];
    float2 v = make_float2(0.0f, 0.0f);
    if ((int)(bv >> 1) == c2) {
      if (bv & 1) v.y = 1.0f; else v.x = 1.0f;
    }
    enc[i] = v;
  }
}

// Finalize: perplexity from counts (exact: counts/2^17), loss mean.
__global__ void vq_fin(float* __restrict__ out, const float* __restrict__ ws) {
  __shared__ float red[8];
  const int t = threadIdx.x;  // 512
  const unsigned* counts = (const unsigned*)ws + 1;
  const float p = (float)counts[t] * (1.0f / 131072.0f);
  float h = p * logf(p + 1e-10f);
#pragma unroll
  for (int off = 32; off > 0; off >>= 1) h += __shfl_down(h, off, 64);
  if ((t & 63) == 0) red[t >> 6] = h;
  __syncthreads();
  if (t == 0) {
    float H = 0.0f;
#pragma unroll
    for (int w = 0; w < 8; ++w) H += red[w];
    out[O_PERP] = expf(-H);
    out[0] = 1.25f * ws[0] * (1.0f / 8388608.0f);
  }
}

extern "C" void kernel_launch(void* const* d_in, const int* in_sizes, int n_in,
                              void* d_out, int out_size, void* d_ws, size_t ws_size,
                              hipStream_t stream) {
  const float* z   = (const float*)d_in[0];
  const float* emb = (const float*)d_in[1];
  float* out = (float*)d_out;
  float* ws  = (float*)d_ws;

  vq_prep<<<1, 512, 0, stream>>>(emb, ws);
  vq_main<<<512, 256, 0, stream>>>(z, emb, out, ws);
  vq_fin<<<1, 512, 0, stream>>>(out, ws);
}

// Round 4
// 542.232 us; speedup vs baseline: 1.1322x; 1.1322x over previous
//
#include <hip/hip_runtime.h>
#include <math.h>

// Problem constants
#define NPIX   131072      // 32*64*64 pixels
#define KCODES 512
#define DIM    64
#define HW     4096        // 64*64
#define CHW    262144      // 64*4096

// Output layout (floats, concatenated in reference return order)
// [0]            quant_loss (1)
// [1]            quantized  (8388608)   [B,C,H,W]
// [8388609]      perplexity (1)
// [8388610]      encodings  (67108864)  [N,512]
// [75497474]     idx        (131072)
#define O_Q    1ll
#define O_PERP 8388609ll
#define O_ENC  8388610ll
#define O_IDX  75497474ll

// ws layout (floats): [0] loss accum, [1..512] counts (u32), [513..1024] esq

// Replicate numpy pairwise_sum of x**2 for n=64:
// 8 accumulators over stride-8 slices, combined ((r0+r1)+(r2+r3))+((r4+r5)+(r6+r7)).
__device__ __forceinline__ float np_sumsq64(const float (&x)[64]) {
#pragma clang fp contract(off)
  float r0 = x[0]*x[0], r1 = x[1]*x[1], r2 = x[2]*x[2], r3 = x[3]*x[3];
  float r4 = x[4]*x[4], r5 = x[5]*x[5], r6 = x[6]*x[6], r7 = x[7]*x[7];
#pragma unroll
  for (int i = 8; i < 64; i += 8) {
    r0 += x[i+0]*x[i+0];
    r1 += x[i+1]*x[i+1];
    r2 += x[i+2]*x[i+2];
    r3 += x[i+3]*x[i+3];
    r4 += x[i+4]*x[i+4];
    r5 += x[i+5]*x[i+5];
    r6 += x[i+6]*x[i+6];
    r7 += x[i+7]*x[i+7];
  }
  return ((r0+r1)+(r2+r3))+((r4+r5)+(r6+r7));
}

// Prep: zero loss accumulator + counts, compute esq[k] (np-pairwise) into ws.
__global__ void vq_prep(const float* __restrict__ emb, float* __restrict__ ws) {
  const int t = threadIdx.x;  // 512 threads
  if (t == 0) ws[0] = 0.0f;
  ((unsigned*)ws)[1 + t] = 0u;
  float x[64];
  const float* e = emb + t * DIM;
#pragma unroll
  for (int d = 0; d < 64; ++d) x[d] = e[d];
  ws[513 + t] = np_sumsq64(x);
}

// Main: one thread = one pixel. za[64] is PINNED into VGPRs via an opaque asm
// register constraint (rounds 1-3 all showed VGPR_Count<=96: the allocator kept
// sinking the z loads into the k-loop, making the inner loop load-bound).
// __launch_bounds__(256,2) matches the true occupancy (2 waves/EU) -> 256 VGPR
// cap. Embedding rows are wave-uniform -> s_load into SGPRs (SMEM pipe); the
// inner loop is then pure v_fmac v,s,v. Single ascending-d fp32 FMA chain
// (mirrors OpenBLAS sgemm accumulation); strict < keeps lowest index on fp32
// ties, matching np.argmin.
__global__ __launch_bounds__(256, 2) void vq_main(
    const float* __restrict__ z, const float* __restrict__ emb,
    float* __restrict__ out, float* __restrict__ ws)
{
  __shared__ unsigned hist[KCODES];     // per-block histogram
  __shared__ unsigned short ridx[256];  // per-row argmin for encodings write
  __shared__ float wsum[4];

  const int t   = threadIdx.x;
  const int blk = blockIdx.x;
  const int n   = blk * 256 + t;        // pixel id, grid = 512 blocks

  hist[t] = 0u;
  hist[t + 256] = 0u;

  // Load this pixel's z vector into registers ([B,C,H,W]: stride HW over c)
  float za[DIM];
  {
    const float* p0 = z + (size_t)(n >> 12) * CHW + (n & 4095);
#pragma unroll
    for (int d = 0; d < DIM; ++d) za[d] = p0[(size_t)d * HW];
  }
  // Pin every za element into a VGPR: the compiler cannot sink/remat the
  // loads past this opaque asm, so the k-loop reads registers, not memory.
#pragma unroll
  for (int d = 0; d < DIM; ++d) asm volatile("" : "+v"(za[d]));

  const float zsqa = np_sumsq64(za);

  const float* __restrict__ esq = ws + 513;
  float best = INFINITY;
  int bi = 0;

  for (int k = 0; k < KCODES; ++k) {
    const float* __restrict__ e = emb + (k << 6);  // wave-uniform -> s_load
    float dot = 0.0f;
#pragma unroll
    for (int d = 0; d < DIM; ++d) dot = fmaf(za[d], e[d], dot);
    const float dist = (zsqa + esq[k]) - 2.0f * dot;  // same rounding as np
    if (dist < best) { best = dist; bi = k; }
  }

  // ---- epilogue ----
  atomicAdd(&hist[bi], 1u);
  ridx[t] = (unsigned short)bi;
  out[O_IDX + n] = (float)bi;

  // quantized output (transposed back to [B,C,H,W]) + loss partial
  float lsum = 0.0f;
  {
    const float* e0 = emb + ((size_t)bi << 6);
    float* q0 = out + O_Q + (size_t)(n >> 12) * CHW + (n & 4095);
#pragma unroll
    for (int d = 0; d < DIM; ++d) {
      const float ev = e0[d];
      const float df = ev - za[d];
      lsum = fmaf(df, df, lsum);
      q0[(size_t)d * HW] = ev;
    }
  }
  // wave + block reduce of loss
#pragma unroll
  for (int off = 32; off > 0; off >>= 1) lsum += __shfl_down(lsum, off, 64);
  if ((t & 63) == 0) wsum[t >> 6] = lsum;
  __syncthreads();  // also publishes hist[] and ridx[]
  if (t == 0) atomicAdd(ws, (wsum[0] + wsum[1]) + (wsum[2] + wsum[3]));

  unsigned* counts = (unsigned*)ws + 1;
  atomicAdd(&counts[t],       hist[t]);
  atomicAdd(&counts[t + 256], hist[t + 256]);

  // encodings: 256 rows x 512 floats per block, one-hot. float2 stores
  // (O_ENC is only 8-byte aligned). Coalesced: consecutive threads write
  // consecutive float2.
  float2* enc = (float2*)(out + O_ENC) + (size_t)blk * (256 * 256);
  for (int i = t; i < 256 * 256; i += 256) {
    const int r  = i >> 8;        // row (local pixel)
    const int c2 = i & 255;       // float2 index within row
    const unsigned bv = ridx[r];
    float2 v = make_float2(0.0f, 0.0f);
    if ((int)(bv >> 1) == c2) {
      if (bv & 1) v.y = 1.0f; else v.x = 1.0f;
    }
    enc[i] = v;
  }
}

// Finalize: perplexity from counts (exact: counts/2^17), loss mean.
__global__ void vq_fin(float* __restrict__ out, const float* __restrict__ ws) {
  __shared__ float red[8];
  const int t = threadIdx.x;  // 512
  const unsigned* counts = (const unsigned*)ws + 1;
  const float p = (float)counts[t] * (1.0f / 131072.0f);
  float h = p * logf(p + 1e-10f);
#pragma unroll
  for (int off = 32; off > 0; off >>= 1) h += __shfl_down(h, off, 64);
  if ((t & 63) == 0) red[t >> 6] = h;
  __syncthreads();
  if (t == 0) {
    float H = 0.0f;
#pragma unroll
    for (int w = 0; w < 8; ++w) H += red[w];
    out[O_PERP] = expf(-H);
    out[0] = 1.25f * ws[0] * (1.0f / 8388608.0f);
  }
}

extern "C" void kernel_launch(void* const* d_in, const int* in_sizes, int n_in,
                              void* d_out, int out_size, void* d_ws, size_t ws_size,
                              hipStream_t stream) {
  const float* z   = (const float*)d_in[0];
  const float* emb = (const float*)d_in[1];
  float* out = (float*)d_out;
  float* ws  = (float*)d_ws;

  vq_prep<<<1, 512, 0, stream>>>(emb, ws);
  vq_main<<<512, 256, 0, stream>>>(z, emb, out, ws);
  vq_fin<<<1, 512, 0, stream>>>(out, ws);
}

// Round 5
// 538.945 us; speedup vs baseline: 1.1391x; 1.0061x over previous
//
#include <hip/hip_runtime.h>
#include <math.h>

// Problem constants
#define NPIX   131072      // 32*64*64 pixels
#define KCODES 512
#define DIM    64
#define HW     4096        // 64*64
#define CHW    262144      // 64*4096

// Output layout (floats, concatenated in reference return order)
// [0]            quant_loss (1)
// [1]            quantized  (8388608)   [B,C,H,W]
// [8388609]      perplexity (1)
// [8388610]      encodings  (67108864)  [N,512]
// [75497474]     idx        (131072)
#define O_Q    1ll
#define O_PERP 8388609ll
#define O_ENC  8388610ll
#define O_IDX  75497474ll

// ws layout (floats): [0] loss accum, [1..512] counts (u32), [513..1024] esq

// Replicate numpy pairwise_sum of x**2 for n=64:
// 8 accumulators over stride-8 slices, combined ((r0+r1)+(r2+r3))+((r4+r5)+(r6+r7)).
__device__ __forceinline__ float np_sumsq64(const float (&x)[64]) {
#pragma clang fp contract(off)
  float r0 = x[0]*x[0], r1 = x[1]*x[1], r2 = x[2]*x[2], r3 = x[3]*x[3];
  float r4 = x[4]*x[4], r5 = x[5]*x[5], r6 = x[6]*x[6], r7 = x[7]*x[7];
#pragma unroll
  for (int i = 8; i < 64; i += 8) {
    r0 += x[i+0]*x[i+0];
    r1 += x[i+1]*x[i+1];
    r2 += x[i+2]*x[i+2];
    r3 += x[i+3]*x[i+3];
    r4 += x[i+4]*x[i+4];
    r5 += x[i+5]*x[i+5];
    r6 += x[i+6]*x[i+6];
    r7 += x[i+7]*x[i+7];
  }
  return ((r0+r1)+(r2+r3))+((r4+r5)+(r6+r7));
}

// Prep: zero loss accumulator + counts, compute esq[k] (np-pairwise) into ws.
__global__ void vq_prep(const float* __restrict__ emb, float* __restrict__ ws) {
  const int t = threadIdx.x;  // 512 threads
  if (t == 0) ws[0] = 0.0f;
  ((unsigned*)ws)[1 + t] = 0u;
  float x[64];
  const float* e = emb + t * DIM;
#pragma unroll
  for (int d = 0; d < 64; ++d) x[d] = e[d];
  ws[513 + t] = np_sumsq64(x);
}

// Main: one thread = one pixel.
// KEY FIX this round: amdgpu_waves_per_eu(2,2). __launch_bounds__'s 2nd arg is
// only a MINIMUM waves/EU — rounds 2-4 showed the allocator still targeting
// 8 waves/EU (64-VGPR budget) and spilling za[64] to scratch (VGPR_Count=48,
// inner loop scratch-load-bound at ~275us). (2,2) pins the occupancy target to
// the grid's true value (512 blk * 4 waves / 256 CU / 4 SIMD = 2 waves/EU),
// raising the budget to 256 VGPRs so za stays register-resident.
// Embedding rows are wave-uniform -> s_load into SGPRs (SGPR_Count=96 confirms
// this already happens); inner loop is then pure v_fmac v,s,v at the issue
// floor. Single ascending-d fp32 FMA chain (mirrors OpenBLAS sgemm
// accumulation); strict < keeps lowest index on fp32 ties, matching np.argmin.
__global__ __launch_bounds__(256)
__attribute__((amdgpu_waves_per_eu(2, 2)))
void vq_main(
    const float* __restrict__ z, const float* __restrict__ emb,
    float* __restrict__ out, float* __restrict__ ws)
{
  __shared__ unsigned hist[KCODES];     // per-block histogram
  __shared__ unsigned short ridx[256];  // per-row argmin for encodings write
  __shared__ float wsum[4];

  const int t   = threadIdx.x;
  const int blk = blockIdx.x;
  const int n   = blk * 256 + t;        // pixel id, grid = 512 blocks

  hist[t] = 0u;
  hist[t + 256] = 0u;

  // Load this pixel's z vector into registers ([B,C,H,W]: stride HW over c)
  float za[DIM];
  {
    const float* p0 = z + (size_t)(n >> 12) * CHW + (n & 4095);
#pragma unroll
    for (int d = 0; d < DIM; ++d) za[d] = p0[(size_t)d * HW];
  }
  // Opaque use: discourage sinking/remat of the z loads into the k-loop.
#pragma unroll
  for (int d = 0; d < DIM; ++d) asm volatile("" : "+v"(za[d]));

  const float zsqa = np_sumsq64(za);

  const float* __restrict__ esq = ws + 513;
  float best = INFINITY;
  int bi = 0;

  for (int k = 0; k < KCODES; ++k) {
    const float* __restrict__ e = emb + (k << 6);  // wave-uniform -> s_load
    float dot = 0.0f;
#pragma unroll
    for (int d = 0; d < DIM; ++d) dot = fmaf(za[d], e[d], dot);
    const float dist = (zsqa + esq[k]) - 2.0f * dot;  // same rounding as np
    if (dist < best) { best = dist; bi = k; }
  }

  // ---- epilogue ----
  atomicAdd(&hist[bi], 1u);
  ridx[t] = (unsigned short)bi;
  out[O_IDX + n] = (float)bi;

  // quantized output (transposed back to [B,C,H,W]) + loss partial
  float lsum = 0.0f;
  {
    const float* e0 = emb + ((size_t)bi << 6);
    float* q0 = out + O_Q + (size_t)(n >> 12) * CHW + (n & 4095);
#pragma unroll
    for (int d = 0; d < DIM; ++d) {
      const float ev = e0[d];
      const float df = ev - za[d];
      lsum = fmaf(df, df, lsum);
      q0[(size_t)d * HW] = ev;
    }
  }
  // wave + block reduce of loss
#pragma unroll
  for (int off = 32; off > 0; off >>= 1) lsum += __shfl_down(lsum, off, 64);
  if ((t & 63) == 0) wsum[t >> 6] = lsum;
  __syncthreads();  // also publishes hist[] and ridx[]
  if (t == 0) atomicAdd(ws, (wsum[0] + wsum[1]) + (wsum[2] + wsum[3]));

  unsigned* counts = (unsigned*)ws + 1;
  atomicAdd(&counts[t],       hist[t]);
  atomicAdd(&counts[t + 256], hist[t + 256]);

  // encodings: 256 rows x 512 floats per block, one-hot. float2 stores
  // (O_ENC is only 8-byte aligned). Coalesced: consecutive threads write
  // consecutive float2.
  float2* enc = (float2*)(out + O_ENC) + (size_t)blk * (256 * 256);
  for (int i = t; i < 256 * 256; i += 256) {
    const int r  = i >> 8;        // row (local pixel)
    const int c2 = i & 255;       // float2 index within row
    const unsigned bv = ridx[r];
    float2 v = make_float2(0.0f, 0.0f);
    if ((int)(bv >> 1) == c2) {
      if (bv & 1) v.y = 1.0f; else v.x = 1.0f;
    }
    enc[i] = v;
  }
}

// Finalize: perplexity from counts (exact: counts/2^17), loss mean.
__global__ void vq_fin(float* __restrict__ out, const float* __restrict__ ws) {
  __shared__ float red[8];
  const int t = threadIdx.x;  // 512
  const unsigned* counts = (const unsigned*)ws + 1;
  const float p = (float)counts[t] * (1.0f / 131072.0f);
  float h = p * logf(p + 1e-10f);
#pragma unroll
  for (int off = 32; off > 0; off >>= 1) h += __shfl_down(h, off, 64);
  if ((t & 63) == 0) red[t >> 6] = h;
  __syncthreads();
  if (t == 0) {
    float H = 0.0f;
#pragma unroll
    for (int w = 0; w < 8; ++w) H += red[w];
    out[O_PERP] = expf(-H);
    out[0] = 1.25f * ws[0] * (1.0f / 8388608.0f);
  }
}

extern "C" void kernel_launch(void* const* d_in, const int* in_sizes, int n_in,
                              void* d_out, int out_size, void* d_ws, size_t ws_size,
                              hipStream_t stream) {
  const float* z   = (const float*)d_in[0];
  const float* emb = (const float*)d_in[1];
  float* out = (float*)d_out;
  float* ws  = (float*)d_ws;

  vq_prep<<<1, 512, 0, stream>>>(emb, ws);
  vq_main<<<512, 256, 0, stream>>>(z, emb, out, ws);
  vq_fin<<<1, 512, 0, stream>>>(out, ws);
}

// Round 6
// 452.536 us; speedup vs baseline: 1.3566x; 1.1909x over previous
//
#include <hip/hip_runtime.h>
#include <math.h>

// Problem constants
#define NPIX   131072      // 32*64*64 pixels
#define KCODES 512
#define DIM    64
#define HW     4096        // 64*64
#define CHW    262144      // 64*4096

// Output layout (floats, concatenated in reference return order)
#define O_Q    1ll
#define O_PERP 8388609ll
#define O_ENC  8388610ll
#define O_IDX  75497474ll

// ws layout (floats): [0] loss accum, [1..512] counts (u32), [513..1024] esq

// Replicate numpy pairwise_sum of x**2 for n=64 (8 accs, stride-8, pairwise combine).
__device__ __forceinline__ float np_sumsq64(const float (&x)[64]) {
#pragma clang fp contract(off)
  float r0 = x[0]*x[0], r1 = x[1]*x[1], r2 = x[2]*x[2], r3 = x[3]*x[3];
  float r4 = x[4]*x[4], r5 = x[5]*x[5], r6 = x[6]*x[6], r7 = x[7]*x[7];
#pragma unroll
  for (int i = 8; i < 64; i += 8) {
    r0 += x[i+0]*x[i+0];
    r1 += x[i+1]*x[i+1];
    r2 += x[i+2]*x[i+2];
    r3 += x[i+3]*x[i+3];
    r4 += x[i+4]*x[i+4];
    r5 += x[i+5]*x[i+5];
    r6 += x[i+6]*x[i+6];
    r7 += x[i+7]*x[i+7];
  }
  return ((r0+r1)+(r2+r3))+((r4+r5)+(r6+r7));
}

// Prep: zero loss accumulator + counts, compute esq[k] (np-pairwise) into ws.
__global__ void vq_prep(const float* __restrict__ emb, float* __restrict__ ws) {
  const int t = threadIdx.x;  // 512 threads
  if (t == 0) ws[0] = 0.0f;
  ((unsigned*)ws)[1 + t] = 0u;
  float x[64];
  const float* e = emb + t * DIM;
#pragma unroll
  for (int d = 0; d < 64; ++d) x[d] = e[d];
  ws[513 + t] = np_sumsq64(x);
}

// Main: GEMM-style register tiling. Block = 256 threads = 64 px x 512 codes.
// Thread (pi=t>>5, ci=t&31) accumulates an 8px x 16code tile in registers.
// Rounds 2-5 proved the wave-uniform SGPR row-fetch structure is latency-walled
// at 274us (only 1 row fits in SGPRs -> no prefetch possible). Here operands
// come from LDS: z_l[d][px] (reads are 32-lane broadcasts, free) and a 16-d
// slice of the TRANSPOSED embedding ET_s[dl][c] (lane ci reads granules
// ci+32q -> 32 consecutive 16B chunks per instruction = conflict-free).
// Per d-step per lane: 6 ds_read_b128 + 128 independent v_fmac -> compute-bound.
// dist math is bitwise-identical to the passing rounds: ascending-d fmaf chain,
// (zsq+esq)-2*dot, ascending-k strict < scan, cross-lane merge tie-breaks to
// lower k => np.argmin semantics exactly.
__global__ __launch_bounds__(256)
__attribute__((amdgpu_waves_per_eu(2, 2)))
void vq_main(
    const float* __restrict__ z, const float* __restrict__ emb,
    float* __restrict__ out, float* __restrict__ ws)
{
  __shared__ float ET_s[16 * 512];   // 32KB: d-slice of transposed embedding
  __shared__ float z_l[64 * 64];     // 16KB: z_l[d][px]
  __shared__ float esq_l[512];
  __shared__ float zsq_l[64];
  __shared__ int   ridx_l[64];

  const int t   = threadIdx.x;
  const int ci  = t & 31;
  const int pi  = t >> 5;            // 0..7
  const int blk = blockIdx.x;        // grid = 2048
  const int n0  = blk * 64;          // 64 consecutive pixels (same batch b)
  const int b   = n0 >> 12;
  const int hw0 = n0 & 4095;
  const float* zg = z + (size_t)b * CHW + hw0;

  esq_l[t]       = ws[513 + t];
  esq_l[t + 256] = ws[513 + 256 + t];

  // Stage z_l[d][px]: 64 rows of 64 floats (coalesced float4 global reads).
  {
    const int i     = t & 15;        // float4 index within row
    const int dbase = t >> 4;        // 0..15
#pragma unroll
    for (int r = 0; r < 4; ++r) {
      const int d = dbase + 16 * r;
      const float4 v = *(const float4*)(zg + (size_t)d * HW + 4 * i);
      *(float4*)&z_l[d * 64 + 4 * i] = v;
    }
  }
  __syncthreads();

  // Exact per-pixel zsq (np pairwise pattern), one thread per pixel.
  if (t < 64) {
    float x[64];
#pragma unroll
    for (int d = 0; d < 64; ++d) x[d] = z_l[d * 64 + t];
    zsq_l[t] = np_sumsq64(x);
  }

  float acc[8][16];
#pragma unroll
  for (int j = 0; j < 8; ++j)
#pragma unroll
    for (int c = 0; c < 16; ++c) acc[j][c] = 0.0f;

  for (int s = 0; s < 4; ++s) {
    __syncthreads();  // previous slice consumed (s=0: doubles as zsq_l publish)
    // Stage ET_s[dl][c] = emb[c][16s+dl] for c = t and t+256.
#pragma unroll
    for (int h = 0; h < 2; ++h) {
      const int c = t + 256 * h;
      const float* er = emb + (size_t)c * 64 + 16 * s;
      const float4 v0 = *(const float4*)(er + 0);
      const float4 v1 = *(const float4*)(er + 4);
      const float4 v2 = *(const float4*)(er + 8);
      const float4 v3 = *(const float4*)(er + 12);
      float tmp[16] = {v0.x, v0.y, v0.z, v0.w, v1.x, v1.y, v1.z, v1.w,
                       v2.x, v2.y, v2.z, v2.w, v3.x, v3.y, v3.z, v3.w};
#pragma unroll
      for (int dl = 0; dl < 16; ++dl) ET_s[dl * 512 + c] = tmp[dl];
    }
    __syncthreads();

#pragma unroll 2
    for (int dl = 0; dl < 16; ++dl) {
      const float* zp = &z_l[(16 * s + dl) * 64 + 8 * pi];
      const float4 za0 = *(const float4*)(zp + 0);
      const float4 za1 = *(const float4*)(zp + 4);
      const float* ep = &ET_s[dl * 512 + 4 * ci];
      const float4 e0 = *(const float4*)(ep + 0);     // codes 4ci+0..3
      const float4 e1 = *(const float4*)(ep + 128);   // codes 128+4ci..
      const float4 e2 = *(const float4*)(ep + 256);   // codes 256+4ci..
      const float4 e3 = *(const float4*)(ep + 384);   // codes 384+4ci..
      const float zr[8]  = {za0.x, za0.y, za0.z, za0.w, za1.x, za1.y, za1.z, za1.w};
      const float er_[16] = {e0.x, e0.y, e0.z, e0.w, e1.x, e1.y, e1.z, e1.w,
                             e2.x, e2.y, e2.z, e2.w, e3.x, e3.y, e3.z, e3.w};
#pragma unroll
      for (int j = 0; j < 8; ++j)
#pragma unroll
        for (int c = 0; c < 16; ++c)
          acc[j][c] = fmaf(zr[j], er_[c], acc[j][c]);
    }
  }

  // ---- argmin epilogue ----
  // Lane's code for acc column (q,r): k = 128q + 4ci + r. Ascending (q,r) scan
  // is ascending global k; strict < keeps lowest index (np.argmin).
  float bd[8];
  int   bk[8];
#pragma unroll
  for (int j = 0; j < 8; ++j) { bd[j] = INFINITY; bk[j] = 0; }
#pragma unroll
  for (int q = 0; q < 4; ++q)
#pragma unroll
    for (int r = 0; r < 4; ++r) {
      const int k = 128 * q + 4 * ci + r;
      const float eq = esq_l[k];
#pragma unroll
      for (int j = 0; j < 8; ++j) {
        const float dist = (zsq_l[8 * pi + j] + eq) - 2.0f * acc[j][4 * q + r];
        if (dist < bd[j]) { bd[j] = dist; bk[j] = k; }
      }
    }
  // Butterfly merge across the 32 ci-lanes (tie-break: lower k), exact.
#pragma unroll
  for (int m = 16; m >= 1; m >>= 1) {
#pragma unroll
    for (int j = 0; j < 8; ++j) {
      const float od = __shfl_xor(bd[j], m, 64);
      const int   ok = __shfl_xor(bk[j], m, 64);
      if (od < bd[j] || (od == bd[j] && ok < bk[j])) { bd[j] = od; bk[j] = ok; }
    }
  }
  if (ci == 0) {
#pragma unroll
    for (int j = 0; j < 8; ++j) ridx_l[8 * pi + j] = bk[j];
  }
  __syncthreads();

  // Wave 0: idx + quantized (coalesced per-d) + loss + counts.
  if (t < 64) {
    const int n = n0 + t;
    const int k = ridx_l[t];
    out[O_IDX + n] = (float)k;
    const float* e0 = emb + ((size_t)k << 6);
    float* q0 = out + O_Q + (size_t)b * CHW + hw0 + t;
    float lsum = 0.0f;
#pragma unroll
    for (int d = 0; d < 64; ++d) {
      const float ev = e0[d];
      const float df = ev - z_l[d * 64 + t];
      lsum = fmaf(df, df, lsum);
      q0[(size_t)d * HW] = ev;
    }
#pragma unroll
    for (int off = 32; off > 0; off >>= 1) lsum += __shfl_down(lsum, off, 64);
    if (t == 0) atomicAdd(ws, lsum);
    atomicAdd((unsigned*)ws + 1 + k, 1u);
  }

  // Encodings: 64 rows x 256 float2, coalesced one-hot stores.
  float2* enc = (float2*)(out + O_ENC) + (size_t)n0 * 256;
  for (int i = t; i < 64 * 256; i += 256) {
    const int r  = i >> 8;
    const int c2 = i & 255;
    const int bv = ridx_l[r];
    float2 v = make_float2(0.0f, 0.0f);
    if ((bv >> 1) == c2) {
      if (bv & 1) v.y = 1.0f; else v.x = 1.0f;
    }
    enc[i] = v;
  }
}

// Finalize: perplexity from counts (exact: counts/2^17), loss mean.
__global__ void vq_fin(float* __restrict__ out, const float* __restrict__ ws) {
  __shared__ float red[8];
  const int t = threadIdx.x;  // 512
  const unsigned* counts = (const unsigned*)ws + 1;
  const float p = (float)counts[t] * (1.0f / 131072.0f);
  float h = p * logf(p + 1e-10f);
#pragma unroll
  for (int off = 32; off > 0; off >>= 1) h += __shfl_down(h, off, 64);
  if ((t & 63) == 0) red[t >> 6] = h;
  __syncthreads();
  if (t == 0) {
    float H = 0.0f;
#pragma unroll
    for (int w = 0; w < 8; ++w) H += red[w];
    out[O_PERP] = expf(-H);
    out[0] = 1.25f * ws[0] * (1.0f / 8388608.0f);
  }
}

extern "C" void kernel_launch(void* const* d_in, const int* in_sizes, int n_in,
                              void* d_out, int out_size, void* d_ws, size_t ws_size,
                              hipStream_t stream) {
  const float* z   = (const float*)d_in[0];
  const float* emb = (const float*)d_in[1];
  float* out = (float*)d_out;
  float* ws  = (float*)d_ws;

  vq_prep<<<1, 512, 0, stream>>>(emb, ws);
  vq_main<<<2048, 256, 0, stream>>>(z, emb, out, ws);
  vq_fin<<<1, 512, 0, stream>>>(out, ws);
}

// Round 7
// 452.062 us; speedup vs baseline: 1.3580x; 1.0010x over previous
//
#include <hip/hip_runtime.h>
#include <math.h>

// Problem constants
#define NPIX   131072      // 32*64*64 pixels
#define KCODES 512
#define DIM    64
#define HW     4096        // 64*64
#define CHW    262144      // 64*4096

// Output layout (floats, concatenated in reference return order)
#define O_Q    1ll
#define O_PERP 8388609ll
#define O_ENC  8388610ll
#define O_IDX  75497474ll

// ws layout (floats): [0] loss accum, [1..512] counts (u32), [513..1024] esq

// Replicate numpy pairwise_sum of x**2 for n=64 (8 accs, stride-8, pairwise combine).
__device__ __forceinline__ float np_sumsq64(const float (&x)[64]) {
#pragma clang fp contract(off)
  float r0 = x[0]*x[0], r1 = x[1]*x[1], r2 = x[2]*x[2], r3 = x[3]*x[3];
  float r4 = x[4]*x[4], r5 = x[5]*x[5], r6 = x[6]*x[6], r7 = x[7]*x[7];
#pragma unroll
  for (int i = 8; i < 64; i += 8) {
    r0 += x[i+0]*x[i+0];
    r1 += x[i+1]*x[i+1];
    r2 += x[i+2]*x[i+2];
    r3 += x[i+3]*x[i+3];
    r4 += x[i+4]*x[i+4];
    r5 += x[i+5]*x[i+5];
    r6 += x[i+6]*x[i+6];
    r7 += x[i+7]*x[i+7];
  }
  return ((r0+r1)+(r2+r3))+((r4+r5)+(r6+r7));
}

// Prep: zero loss accumulator + counts, compute esq[k] (np-pairwise) into ws.
__global__ void vq_prep(const float* __restrict__ emb, float* __restrict__ ws) {
  const int t = threadIdx.x;  // 512 threads
  if (t == 0) ws[0] = 0.0f;
  ((unsigned*)ws)[1 + t] = 0u;
  float x[64];
  const float* e = emb + t * DIM;
#pragma unroll
  for (int d = 0; d < 64; ++d) x[d] = e[d];
  ws[513 + t] = np_sumsq64(x);
}

// Main: GEMM-style register tiling, round-7 occupancy fix.
// Block = 256 threads = 64 px x 512 codes, processed as TWO 256-code halves.
// Thread (pi=t>>5, ci=t&31) accumulates an 8px x 8code tile per half (acc=64
// VGPRs, vs round 6's 128) -> total ~100 VGPRs -> waves_per_eu(4,4) budget
// (128) fits. LDS ~35KB (ET slice = 16d x 256c) -> 4 blocks/CU, 4 waves/SIMD:
// syncthreads / staging latency / epilogue now overlap across 4 resident
// blocks (round 6 had only 2 waves/SIMD -> ~195us vs ~90us model).
// dist math bitwise-identical to all passing rounds: ascending-d fmaf chain,
// (zsq+esq)-2*dot, ascending-k scan (H asc, q asc, r asc), strict <, butterfly
// merge tie-breaks to lower k => np.argmin semantics exactly.
__global__ __launch_bounds__(256)
__attribute__((amdgpu_waves_per_eu(4, 4)))
void vq_main(
    const float* __restrict__ z, const float* __restrict__ emb,
    float* __restrict__ out, float* __restrict__ ws)
{
  __shared__ float ET_s[16 * 256];   // 16KB: 16-d slice of embT, one code-half
  __shared__ float z_l[64 * 64];     // 16KB: z_l[d][px]
  __shared__ float esq_l[512];
  __shared__ float zsq_l[64];
  __shared__ int   ridx_l[64];
  __shared__ float wsum[4];

  const int t   = threadIdx.x;
  const int ci  = t & 31;
  const int pi  = t >> 5;            // 0..7
  const int blk = blockIdx.x;        // grid = 2048
  const int n0  = blk * 64;          // 64 consecutive pixels (same batch b)
  const int b   = n0 >> 12;
  const int hw0 = n0 & 4095;
  const float* zg = z + (size_t)b * CHW + hw0;

  esq_l[t]       = ws[513 + t];
  esq_l[t + 256] = ws[769 + t];

  // Stage z_l[d][px]: 64 rows of 64 floats (coalesced float4 global reads).
  {
    const int i     = t & 15;        // float4 index within row
    const int dbase = t >> 4;        // 0..15
#pragma unroll
    for (int r = 0; r < 4; ++r) {
      const int d = dbase + 16 * r;
      const float4 v = *(const float4*)(zg + (size_t)d * HW + 4 * i);
      *(float4*)&z_l[d * 64 + 4 * i] = v;
    }
  }
  __syncthreads();

  // Exact per-pixel zsq (np pairwise pattern), one thread per pixel.
  if (t < 64) {
    float x[64];
#pragma unroll
    for (int d = 0; d < 64; ++d) x[d] = z_l[d * 64 + t];
    zsq_l[t] = np_sumsq64(x);
  }

  float bd[8];
  int   bk[8];
#pragma unroll
  for (int j = 0; j < 8; ++j) { bd[j] = INFINITY; bk[j] = 0; }

  for (int H = 0; H < 2; ++H) {
    float acc[8][8];
#pragma unroll
    for (int j = 0; j < 8; ++j)
#pragma unroll
      for (int c = 0; c < 8; ++c) acc[j][c] = 0.0f;

    for (int s = 0; s < 4; ++s) {
      __syncthreads();  // previous slice consumed (first: z_l/zsq_l published)
      // Stage ET_s[dl][c] = emb[256H + c][16s + dl], c = t.
      {
        const float* er = emb + (size_t)(256 * H + t) * 64 + 16 * s;
        const float4 v0 = *(const float4*)(er + 0);
        const float4 v1 = *(const float4*)(er + 4);
        const float4 v2 = *(const float4*)(er + 8);
        const float4 v3 = *(const float4*)(er + 12);
        float tmp[16] = {v0.x, v0.y, v0.z, v0.w, v1.x, v1.y, v1.z, v1.w,
                         v2.x, v2.y, v2.z, v2.w, v3.x, v3.y, v3.z, v3.w};
#pragma unroll
        for (int dl = 0; dl < 16; ++dl) ET_s[dl * 256 + t] = tmp[dl];
      }
      __syncthreads();

#pragma unroll 2
      for (int dl = 0; dl < 16; ++dl) {
        const float* zp = &z_l[(16 * s + dl) * 64 + 8 * pi];
        const float4 za0 = *(const float4*)(zp + 0);
        const float4 za1 = *(const float4*)(zp + 4);
        const float* ep = &ET_s[dl * 256 + 4 * ci];
        const float4 e0 = *(const float4*)(ep + 0);     // codes 256H+4ci+0..3
        const float4 e1 = *(const float4*)(ep + 128);   // codes 256H+128+4ci..
        const float zr[8] = {za0.x, za0.y, za0.z, za0.w,
                             za1.x, za1.y, za1.z, za1.w};
        const float er_[8] = {e0.x, e0.y, e0.z, e0.w,
                              e1.x, e1.y, e1.z, e1.w};
#pragma unroll
        for (int j = 0; j < 8; ++j)
#pragma unroll
          for (int c = 0; c < 8; ++c)
            acc[j][c] = fmaf(zr[j], er_[c], acc[j][c]);
      }
    }

    // dist + running argmin for this half; ascending (q,r) = ascending k.
#pragma unroll
    for (int q = 0; q < 2; ++q)
#pragma unroll
      for (int r = 0; r < 4; ++r) {
        const int k = 256 * H + 128 * q + 4 * ci + r;
        const float eq = esq_l[k];
#pragma unroll
        for (int j = 0; j < 8; ++j) {
          const float dist = (zsq_l[8 * pi + j] + eq) - 2.0f * acc[j][4 * q + r];
          if (dist < bd[j]) { bd[j] = dist; bk[j] = k; }
        }
      }
  }

  // Butterfly merge across the 32 ci-lanes (tie-break: lower k), exact.
#pragma unroll
  for (int m = 16; m >= 1; m >>= 1) {
#pragma unroll
    for (int j = 0; j < 8; ++j) {
      const float od = __shfl_xor(bd[j], m, 64);
      const int   ok = __shfl_xor(bk[j], m, 64);
      if (od < bd[j] || (od == bd[j] && ok < bk[j])) { bd[j] = od; bk[j] = ok; }
    }
  }
  if (ci == 0) {
#pragma unroll
    for (int j = 0; j < 8; ++j) ridx_l[8 * pi + j] = bk[j];
  }
  __syncthreads();

  // ---- epilogue (all 4 waves) ----
  if (t < 64) {
    const int k = ridx_l[t];
    out[O_IDX + n0 + t] = (float)k;
    atomicAdd((unsigned*)ws + 1 + k, 1u);
  }

  // quantized (transposed back to [B,C,H,W]) + loss, distributed: thread
  // (px = t&63, dq = t>>6) handles 16 d's of one pixel; stores coalesced.
  {
    const int px = t & 63;
    const int dq = t >> 6;
    const int k  = ridx_l[px];
    const float* e0 = emb + ((size_t)k << 6);
    float* q0 = out + O_Q + (size_t)b * CHW + hw0 + px;
    float lsum = 0.0f;
#pragma unroll
    for (int j = 0; j < 16; ++j) {
      const int d = dq * 16 + j;
      const float ev = e0[d];
      const float df = ev - z_l[d * 64 + px];
      lsum = fmaf(df, df, lsum);
      q0[(size_t)d * HW] = ev;
    }
#pragma unroll
    for (int off = 32; off > 0; off >>= 1) lsum += __shfl_down(lsum, off, 64);
    if ((t & 63) == 0) wsum[t >> 6] = lsum;
  }
  __syncthreads();
  if (t == 0) atomicAdd(ws, (wsum[0] + wsum[1]) + (wsum[2] + wsum[3]));

  // Encodings: 64 rows x 256 float2, coalesced one-hot stores.
  float2* enc = (float2*)(out + O_ENC) + (size_t)n0 * 256;
  for (int i = t; i < 64 * 256; i += 256) {
    const int r  = i >> 8;
    const int c2 = i & 255;
    const int bv = ridx_l[r];
    float2 v = make_float2(0.0f, 0.0f);
    if ((bv >> 1) == c2) {
      if (bv & 1) v.y = 1.0f; else v.x = 1.0f;
    }
    enc[i] = v;
  }
}

// Finalize: perplexity from counts (exact: counts/2^17), loss mean.
__global__ void vq_fin(float* __restrict__ out, const float* __restrict__ ws) {
  __shared__ float red[8];
  const int t = threadIdx.x;  // 512
  const unsigned* counts = (const unsigned*)ws + 1;
  const float p = (float)counts[t] * (1.0f / 131072.0f);
  float h = p * logf(p + 1e-10f);
#pragma unroll
  for (int off = 32; off > 0; off >>= 1) h += __shfl_down(h, off, 64);
  if ((t & 63) == 0) red[t >> 6] = h;
  __syncthreads();
  if (t == 0) {
    float H = 0.0f;
#pragma unroll
    for (int w = 0; w < 8; ++w) H += red[w];
    out[O_PERP] = expf(-H);
    out[0] = 1.25f * ws[0] * (1.0f / 8388608.0f);
  }
}

extern "C" void kernel_launch(void* const* d_in, const int* in_sizes, int n_in,
                              void* d_out, int out_size, void* d_ws, size_t ws_size,
                              hipStream_t stream) {
  const float* z   = (const float*)d_in[0];
  const float* emb = (const float*)d_in[1];
  float* out = (float*)d_out;
  float* ws  = (float*)d_ws;

  vq_prep<<<1, 512, 0, stream>>>(emb, ws);
  vq_main<<<2048, 256, 0, stream>>>(z, emb, out, ws);
  vq_fin<<<1, 512, 0, stream>>>(out, ws);
}